// Round 8
// baseline (122.579 us; speedup 1.0000x reference)
//
#include <hip/hip_runtime.h>
#include <hip/hip_bf16.h>

typedef __attribute__((ext_vector_type(4))) float f32x4;
typedef __attribute__((ext_vector_type(8))) short bf16x8;

__device__ __forceinline__ unsigned short f2bf(float f) {
    unsigned int u = __float_as_uint(f);
    u = (u + 0x7FFFu + ((u >> 16) & 1u)) >> 16;
    return (unsigned short)u;
}

__device__ __forceinline__ float bf2f(unsigned short u) {
    return __uint_as_float(((unsigned int)u) << 16);
}

// Fused conversion: blocks [0,12500) convert features (200000*128 f32 -> bf16),
// blocks [12500,12628) convert W1|W2 (2*128*256).
__global__ __launch_bounds__(256) void cvt_fused(const float* __restrict__ feat,
                                                 const float* __restrict__ W1,
                                                 const float* __restrict__ W2,
                                                 unsigned short* __restrict__ featb,
                                                 unsigned short* __restrict__ W1b,
                                                 unsigned short* __restrict__ W2b) {
    if (blockIdx.x < 12500) {
        size_t i = ((size_t)blockIdx.x * 256 + threadIdx.x) * 8;
        f32x4 a = __builtin_nontemporal_load((const f32x4*)(feat + i));
        f32x4 b = __builtin_nontemporal_load((const f32x4*)(feat + i + 4));
        bf16x8 o;
        o[0] = (short)f2bf(a[0]); o[1] = (short)f2bf(a[1]);
        o[2] = (short)f2bf(a[2]); o[3] = (short)f2bf(a[3]);
        o[4] = (short)f2bf(b[0]); o[5] = (short)f2bf(b[1]);
        o[6] = (short)f2bf(b[2]); o[7] = (short)f2bf(b[3]);
        *(bf16x8*)(featb + i) = o;
    } else {
        int i = (blockIdx.x - 12500) * 256 + threadIdx.x;   // [0, 32768)
        W1b[i] = f2bf(__builtin_nontemporal_load(W1 + i));
        W2b[i] = f2bf(__builtin_nontemporal_load(W2 + i));
    }
}

// Pure gather+mean kernel (the latency-vs-fabric experiment):
// comb[m] = [ src[self[m]] | mean_s src[neigh[m][s]] ]  (bf16 [M][256])
// No LDS, no barriers, no launch_bounds cap: waves fully independent,
// VGPR target <=64 (5+5 neighbor batches) -> 32 waves/CU.
__global__ void sage_agg(const unsigned short* __restrict__ src,   // [*,128] bf16
                         const int* __restrict__ self_idx,
                         const int* __restrict__ neigh_idx,
                         unsigned short* __restrict__ comb) {      // [M][256] bf16
    const int t = threadIdx.x;
    const int m = blockIdx.x * 16 + (t >> 4);
    const int co = (t & 15) * 8;

    const int si = self_idx[m];
    int ni[10];
    #pragma unroll
    for (int j = 0; j < 10; ++j) ni[j] = neigh_idx[m * 10 + j];

    bf16x8 sv = *(const bf16x8*)(src + (size_t)si * 128 + co);

    float s[8];
    #pragma unroll
    for (int e = 0; e < 8; ++e) s[e] = 0.f;

    // batch 1: neighbors 0..4
    {
        bf16x8 nv[5];
        #pragma unroll
        for (int j = 0; j < 5; ++j)
            nv[j] = *(const bf16x8*)(src + (size_t)ni[j] * 128 + co);
        #pragma unroll
        for (int j = 0; j < 5; ++j) {
            #pragma unroll
            for (int e = 0; e < 8; ++e) s[e] += bf2f((unsigned short)nv[j][e]);
        }
    }
    // batch 2: neighbors 5..9
    {
        bf16x8 nv[5];
        #pragma unroll
        for (int j = 0; j < 5; ++j)
            nv[j] = *(const bf16x8*)(src + (size_t)ni[5 + j] * 128 + co);
        #pragma unroll
        for (int j = 0; j < 5; ++j) {
            #pragma unroll
            for (int e = 0; e < 8; ++e) s[e] += bf2f((unsigned short)nv[j][e]);
        }
    }

    bf16x8 o;
    #pragma unroll
    for (int e = 0; e < 8; ++e) o[e] = (short)f2bf(s[e] * 0.1f);

    unsigned short* cp = comb + (size_t)m * 256;
    *(bf16x8*)(cp + co) = sv;
    *(bf16x8*)(cp + 128 + co) = o;
}

// Dense streaming GEMM: out = relu(comb @ W^T), comb [M][256] bf16, W [128][256].
// 64 rows/block, 4 waves x (16 rows x 128 cols), K=256.
template<bool OUT_BF16>
__global__ __launch_bounds__(256, 4)
void sage_gemm(const unsigned short* __restrict__ comb,
               const unsigned short* __restrict__ Wb,
               void* __restrict__ out_v) {
    __shared__ unsigned short As[64][264];   // +8 pad (row 528B)

    const int t = threadIdx.x;
    const int rowBase = blockIdx.x * 64;

    // Stage 64x256 tile: fully coalesced 16B loads (4KB contiguous per it).
    #pragma unroll
    for (int it = 0; it < 8; ++it) {
        int i = it * 256 + t;           // 0..2047
        int row = i >> 5, ch = i & 31;  // 32 chunks of 8 bf16 per row
        bf16x8 v = *(const bf16x8*)(comb + (size_t)(rowBase + row) * 256 + ch * 8);
        *(bf16x8*)&As[row][ch * 8] = v;
    }
    __syncthreads();

    const int lane = t & 63;
    const int w = t >> 6;
    const int arow = w * 16 + (lane & 15);
    const int ko = (lane >> 4) * 8;
    const int ncol = lane & 15;

    f32x4 acc[8];
    #pragma unroll
    for (int i = 0; i < 8; ++i) acc[i] = (f32x4){0.f, 0.f, 0.f, 0.f};

    #pragma unroll
    for (int kk = 0; kk < 8; ++kk) {
        bf16x8 af = *(const bf16x8*)&As[arow][kk * 32 + ko];
        #pragma unroll
        for (int ct = 0; ct < 8; ++ct) {
            const unsigned short* wp = Wb + (ct * 16 + ncol) * 256 + kk * 32 + ko;
            bf16x8 bf = *(const bf16x8*)wp;
            acc[ct] = __builtin_amdgcn_mfma_f32_16x16x32_bf16(af, bf, acc[ct], 0, 0, 0);
        }
    }

    // C/D: col = lane&15, row = (lane>>4)*4 + r
    const int mr = rowBase + w * 16 + (lane >> 4) * 4;
    if (OUT_BF16) {
        unsigned short* out = (unsigned short*)out_v;
        #pragma unroll
        for (int ct = 0; ct < 8; ++ct) {
            #pragma unroll
            for (int r = 0; r < 4; ++r) {
                out[(size_t)(mr + r) * 128 + ct * 16 + ncol] = f2bf(fmaxf(acc[ct][r], 0.f));
            }
        }
    } else {
        float* out = (float*)out_v;
        #pragma unroll
        for (int ct = 0; ct < 8; ++ct) {
            #pragma unroll
            for (int r = 0; r < 4; ++r) {
                out[(size_t)(mr + r) * 128 + ct * 16 + ncol] = fmaxf(acc[ct][r], 0.f);
            }
        }
    }
}

// Fused layer (round-3/7 proven config): used for layer 2 (and as mid fallback).
template<bool OUT_BF16>
__global__ __launch_bounds__(256, 4)
void sage_layer32(const unsigned short* __restrict__ src,
                  const unsigned short* __restrict__ Wb,
                  const int* __restrict__ self_idx,
                  const int* __restrict__ neigh_idx,
                  void* __restrict__ out_v) {
    __shared__ unsigned short As[32][264];
    __shared__ int sIdx[32];
    __shared__ int nIdx[320];

    const int t = threadIdx.x;
    const int rowBase = blockIdx.x * 32;

    if (t < 32) sIdx[t] = self_idx[rowBase + t];
    for (int i = t; i < 320; i += 256) nIdx[i] = neigh_idx[rowBase * 10 + i];
    __syncthreads();

    const int r0 = t >> 4;
    const int r1 = r0 + 16;
    const int co = (t & 15) * 8;

    bf16x8 sv0 = *(const bf16x8*)(src + (size_t)sIdx[r0] * 128 + co);
    bf16x8 sv1 = *(const bf16x8*)(src + (size_t)sIdx[r1] * 128 + co);
    bf16x8 nv0[10], nv1[10];
    #pragma unroll
    for (int sn = 0; sn < 10; ++sn)
        nv0[sn] = *(const bf16x8*)(src + (size_t)nIdx[r0 * 10 + sn] * 128 + co);
    #pragma unroll
    for (int sn = 0; sn < 10; ++sn)
        nv1[sn] = *(const bf16x8*)(src + (size_t)nIdx[r1 * 10 + sn] * 128 + co);

    *(bf16x8*)&As[r0][co] = sv0;
    *(bf16x8*)&As[r1][co] = sv1;

    float s0[8], s1[8];
    #pragma unroll
    for (int e = 0; e < 8; ++e) { s0[e] = 0.f; s1[e] = 0.f; }
    #pragma unroll
    for (int sn = 0; sn < 10; ++sn) {
        #pragma unroll
        for (int e = 0; e < 8; ++e) s0[e] += bf2f((unsigned short)nv0[sn][e]);
    }
    #pragma unroll
    for (int sn = 0; sn < 10; ++sn) {
        #pragma unroll
        for (int e = 0; e < 8; ++e) s1[e] += bf2f((unsigned short)nv1[sn][e]);
    }
    bf16x8 o0, o1;
    #pragma unroll
    for (int e = 0; e < 8; ++e) {
        o0[e] = (short)f2bf(s0[e] * 0.1f);
        o1[e] = (short)f2bf(s1[e] * 0.1f);
    }
    *(bf16x8*)&As[r0][128 + co] = o0;
    *(bf16x8*)&As[r1][128 + co] = o1;
    __syncthreads();

    const int lane = t & 63;
    const int w = t >> 6;
    const int rows16 = (w & 1) * 16;
    const int cols64 = (w >> 1) * 64;
    const int arow = rows16 + (lane & 15);
    const int ko = (lane >> 4) * 8;
    const int ncol = lane & 15;

    f32x4 acc[4];
    #pragma unroll
    for (int i = 0; i < 4; ++i) acc[i] = (f32x4){0.f, 0.f, 0.f, 0.f};

    #pragma unroll
    for (int kk = 0; kk < 8; ++kk) {
        bf16x8 af = *(const bf16x8*)&As[arow][kk * 32 + ko];
        #pragma unroll
        for (int ct = 0; ct < 4; ++ct) {
            const unsigned short* wp = Wb + (size_t)(cols64 + ct * 16 + ncol) * 256 + kk * 32 + ko;
            bf16x8 bf = *(const bf16x8*)wp;
            acc[ct] = __builtin_amdgcn_mfma_f32_16x16x32_bf16(af, bf, acc[ct], 0, 0, 0);
        }
    }

    const int mr = rowBase + rows16 + (lane >> 4) * 4;
    if (OUT_BF16) {
        unsigned short* out = (unsigned short*)out_v;
        #pragma unroll
        for (int ct = 0; ct < 4; ++ct) {
            #pragma unroll
            for (int r = 0; r < 4; ++r) {
                out[(size_t)(mr + r) * 128 + cols64 + ct * 16 + ncol] = f2bf(fmaxf(acc[ct][r], 0.f));
            }
        }
    } else {
        float* out = (float*)out_v;
        #pragma unroll
        for (int ct = 0; ct < 4; ++ct) {
            #pragma unroll
            for (int r = 0; r < 4; ++r) {
                out[(size_t)(mr + r) * 128 + cols64 + ct * 16 + ncol] = fmaxf(acc[ct][r], 0.f);
            }
        }
    }
}

// ---- Fallback (f32-source) layer kernel, used only if ws is too small ----
template<bool SRC_BF16, bool OUT_BF16>
__global__ __launch_bounds__(256, 2)
void sage_layer(const void* __restrict__ src_v,
                const unsigned short* __restrict__ Wb,
                const int* __restrict__ self_idx,
                const int* __restrict__ neigh_idx,
                void* __restrict__ out_v) {
    __shared__ unsigned short As[64][264];
    __shared__ int sIdx[64];
    __shared__ int nIdx[64][10];

    const int t = threadIdx.x;
    const int rowBase = blockIdx.x * 64;

    if (t < 64) sIdx[t] = self_idx[rowBase + t];
    for (int i = t; i < 640; i += 256) nIdx[i / 10][i % 10] = neigh_idx[rowBase * 10 + i];
    __syncthreads();

    #pragma unroll
    for (int it = 0; it < 16; ++it) {
        int c = it * 256 + t;
        int row = c >> 6;
        int cc = c & 63;
        float4 v;
        if (cc < 32) {
            if constexpr (SRC_BF16) {
                ushort4 u = *(const ushort4*)((const unsigned short*)src_v + (size_t)sIdx[row] * 128 + cc * 4);
                v.x = bf2f(u.x); v.y = bf2f(u.y); v.z = bf2f(u.z); v.w = bf2f(u.w);
            } else {
                v = *(const float4*)((const float*)src_v + (size_t)sIdx[row] * 128 + cc * 4);
            }
        } else {
            int fo = (cc - 32) * 4;
            float sx = 0.f, sy = 0.f, sz = 0.f, sw = 0.f;
            #pragma unroll
            for (int sn = 0; sn < 10; ++sn) {
                float4 x;
                if constexpr (SRC_BF16) {
                    ushort4 u = *(const ushort4*)((const unsigned short*)src_v + (size_t)nIdx[row][sn] * 128 + fo);
                    x.x = bf2f(u.x); x.y = bf2f(u.y); x.z = bf2f(u.z); x.w = bf2f(u.w);
                } else {
                    x = *(const float4*)((const float*)src_v + (size_t)nIdx[row][sn] * 128 + fo);
                }
                sx += x.x; sy += x.y; sz += x.z; sw += x.w;
            }
            v.x = sx * 0.1f; v.y = sy * 0.1f; v.z = sz * 0.1f; v.w = sw * 0.1f;
        }
        ushort4 o;
        o.x = f2bf(v.x); o.y = f2bf(v.y); o.z = f2bf(v.z); o.w = f2bf(v.w);
        *(ushort4*)&As[row][cc * 4] = o;
    }
    __syncthreads();

    const int lane = t & 63;
    const int w = t >> 6;
    const int arow = w * 16 + (lane & 15);
    const int ko = (lane >> 4) * 8;
    const int ncol = lane & 15;

    f32x4 acc[8];
    #pragma unroll
    for (int i = 0; i < 8; ++i) acc[i] = (f32x4){0.f, 0.f, 0.f, 0.f};

    #pragma unroll
    for (int kk = 0; kk < 8; ++kk) {
        bf16x8 af = *(const bf16x8*)&As[arow][kk * 32 + ko];
        #pragma unroll
        for (int ct = 0; ct < 8; ++ct) {
            const unsigned short* wp = Wb + (ct * 16 + ncol) * 256 + kk * 32 + ko;
            bf16x8 bf = *(const bf16x8*)wp;
            acc[ct] = __builtin_amdgcn_mfma_f32_16x16x32_bf16(af, bf, acc[ct], 0, 0, 0);
        }
    }

    const int mr = rowBase + w * 16 + (lane >> 4) * 4;
    if (OUT_BF16) {
        unsigned short* out = (unsigned short*)out_v;
        #pragma unroll
        for (int ct = 0; ct < 8; ++ct) {
            #pragma unroll
            for (int r = 0; r < 4; ++r) {
                out[(size_t)(mr + r) * 128 + ct * 16 + ncol] = f2bf(fmaxf(acc[ct][r], 0.f));
            }
        }
    } else {
        float* out = (float*)out_v;
        #pragma unroll
        for (int ct = 0; ct < 8; ++ct) {
            #pragma unroll
            for (int r = 0; r < 4; ++r) {
                out[(size_t)(mr + r) * 128 + ct * 16 + ncol] = fmaxf(acc[ct][r], 0.f);
            }
        }
    }
}

extern "C" void kernel_launch(void* const* d_in, const int* in_sizes, int n_in,
                              void* d_out, int out_size, void* d_ws, size_t ws_size,
                              hipStream_t stream) {
    const float* raw   = (const float*)d_in[0];   // [200000,128]
    const float* W1    = (const float*)d_in[1];   // [128,256]
    const float* W2    = (const float*)d_in[2];   // [128,256]
    const int* self1   = (const int*)d_in[3];     // [81920]
    const int* neigh1  = (const int*)d_in[4];     // [81920,10]
    const int* self2   = (const int*)d_in[5];     // [8192]
    const int* neigh2  = (const int*)d_in[6];     // [8192,10]
    float* out = (float*)d_out;                   // [8192,128] f32

    char* ws = (char*)d_ws;
    unsigned short* W1b  = (unsigned short*)ws;                        // 32768 elems
    unsigned short* W2b  = W1b + 128 * 256;
    unsigned short* h1   = W2b + 128 * 256;                            // 81920*128
    unsigned short* rawb = h1 + (size_t)81920 * 128;                   // 200000*128
    unsigned short* comb = rawb + (size_t)200000 * 128;                // 81920*256

    const size_t need_mid  = (size_t)(128 * 256 * 2 + 81920 * 128 + (size_t)200000 * 128) * 2;
    const size_t need_full = need_mid + (size_t)81920 * 256 * 2;

    cvt_fused<<<12628, 256, 0, stream>>>(raw, W1, W2, rawb, W1b, W2b);

    if (ws_size >= need_full) {
        // Decoupled layer 1: pure gather (max occupancy) + dense GEMM.
        sage_agg<<<81920 / 16, 256, 0, stream>>>(rawb, self1, neigh1, comb);
        sage_gemm<true><<<81920 / 64, 256, 0, stream>>>(comb, W1b, (void*)h1);
        // Layer 2: fused (small).
        sage_layer32<false><<<8192 / 32, 256, 0, stream>>>(
            h1, W2b, self2, neigh2, (void*)out);
    } else if (ws_size >= need_mid) {
        sage_layer32<true><<<81920 / 32, 256, 0, stream>>>(
            rawb, W1b, self1, neigh1, (void*)h1);
        sage_layer32<false><<<8192 / 32, 256, 0, stream>>>(
            h1, W2b, self2, neigh2, (void*)out);
    } else {
        sage_layer<false, true><<<81920 / 64, 256, 0, stream>>>(
            (const void*)raw, W1b, self1, neigh1, (void*)h1);
        sage_layer<true, false><<<8192 / 64, 256, 0, stream>>>(
            (const void*)h1, W2b, self2, neigh2, (void*)out);
    }
}

// Round 9
// 92.863 us; speedup vs baseline: 1.3200x; 1.3200x over previous
//
#include <hip/hip_runtime.h>
#include <hip/hip_bf16.h>

typedef __attribute__((ext_vector_type(4))) float f32x4;
typedef __attribute__((ext_vector_type(2))) float f32x2;
typedef __attribute__((ext_vector_type(8))) short bf16x8;

__device__ __forceinline__ unsigned short f2bf(float f) {
    unsigned int u = __float_as_uint(f);
    u = (u + 0x7FFFu + ((u >> 16) & 1u)) >> 16;
    return (unsigned short)u;
}

__device__ __forceinline__ float bf2f(unsigned short u) {
    return __uint_as_float(((unsigned int)u) << 16);
}

// Fused conversion: blocks [0,12500) convert features (200000*128) to BOTH
// bf16 (self reads / fallback) and fp8 e4m3 (neighbor reads, half the bytes);
// blocks [12500,12628) convert W1|W2 to bf16.
__global__ __launch_bounds__(256) void cvt_fused(const float* __restrict__ feat,
                                                 const float* __restrict__ W1,
                                                 const float* __restrict__ W2,
                                                 unsigned short* __restrict__ featb,
                                                 unsigned int* __restrict__ feat8,  // packed 4x fp8
                                                 unsigned short* __restrict__ W1b,
                                                 unsigned short* __restrict__ W2b) {
    if (blockIdx.x < 12500) {
        size_t i = ((size_t)blockIdx.x * 256 + threadIdx.x) * 8;
        f32x4 a = __builtin_nontemporal_load((const f32x4*)(feat + i));
        f32x4 b = __builtin_nontemporal_load((const f32x4*)(feat + i + 4));
        bf16x8 o;
        o[0] = (short)f2bf(a[0]); o[1] = (short)f2bf(a[1]);
        o[2] = (short)f2bf(a[2]); o[3] = (short)f2bf(a[3]);
        o[4] = (short)f2bf(b[0]); o[5] = (short)f2bf(b[1]);
        o[6] = (short)f2bf(b[2]); o[7] = (short)f2bf(b[3]);
        *(bf16x8*)(featb + i) = o;
        // fp8 e4m3 pack: two u32s of 4 bytes each.
        unsigned int p0 = 0, p1 = 0;
        p0 = __builtin_amdgcn_cvt_pk_fp8_f32(a[0], a[1], p0, false);
        p0 = __builtin_amdgcn_cvt_pk_fp8_f32(a[2], a[3], p0, true);
        p1 = __builtin_amdgcn_cvt_pk_fp8_f32(b[0], b[1], p1, false);
        p1 = __builtin_amdgcn_cvt_pk_fp8_f32(b[2], b[3], p1, true);
        uint2 pv; pv.x = p0; pv.y = p1;
        *(uint2*)(feat8 + i / 4) = pv;
    } else {
        int i = (blockIdx.x - 12500) * 256 + threadIdx.x;   // [0, 32768)
        W1b[i] = f2bf(__builtin_nontemporal_load(W1 + i));
        W2b[i] = f2bf(__builtin_nontemporal_load(W2 + i));
    }
}

// Layer 1 fused, fp8 neighbor gather:
// out[m] = relu([srcb[self[m]] | mean_s src8[neigh[m][s]]] @ W^T)
// 32 rows/block, 256 threads, round-3/7 proven structure + launch_bounds(256,4).
__global__ __launch_bounds__(256, 4)
void sage_layer32_f8(const unsigned short* __restrict__ srcb,  // [*,128] bf16 (self)
                     const unsigned int* __restrict__ src8,    // [*,32] u32 = 128 fp8 (neigh)
                     const unsigned short* __restrict__ Wb,    // [128][256] bf16 row-major
                     const int* __restrict__ self_idx,
                     const int* __restrict__ neigh_idx,
                     unsigned short* __restrict__ out) {       // [M,128] bf16
    __shared__ unsigned short As[32][264];   // [self|agg] rows, +8 pad (row 528B)
    __shared__ int sIdx[32];
    __shared__ int nIdx[320];

    const int t = threadIdx.x;
    const int rowBase = blockIdx.x * 32;

    if (t < 32) sIdx[t] = self_idx[rowBase + t];
    for (int i = t; i < 320; i += 256) nIdx[i] = neigh_idx[rowBase * 10 + i];
    __syncthreads();

    const int r0 = t >> 4;          // rows 0..15
    const int r1 = r0 + 16;         // rows 16..31
    const int c8 = (t & 15) * 8;    // element offset of this thread's 8-elem chunk
    const int cu = (t & 15) * 2;    // u32 offset within a 32-u32 fp8 row

    // Issue gather loads: 2 self (16B bf16) + 20 neighbor (8B fp8).
    bf16x8 sv0 = *(const bf16x8*)(srcb + (size_t)sIdx[r0] * 128 + c8);
    bf16x8 sv1 = *(const bf16x8*)(srcb + (size_t)sIdx[r1] * 128 + c8);
    uint2 nv0[10], nv1[10];
    #pragma unroll
    for (int sn = 0; sn < 10; ++sn)
        nv0[sn] = *(const uint2*)(src8 + (size_t)nIdx[r0 * 10 + sn] * 32 + cu);
    #pragma unroll
    for (int sn = 0; sn < 10; ++sn)
        nv1[sn] = *(const uint2*)(src8 + (size_t)nIdx[r1 * 10 + sn] * 32 + cu);

    *(bf16x8*)&As[r0][c8] = sv0;
    *(bf16x8*)&As[r1][c8] = sv1;

    float s0[8], s1[8];
    #pragma unroll
    for (int e = 0; e < 8; ++e) { s0[e] = 0.f; s1[e] = 0.f; }
    #pragma unroll
    for (int sn = 0; sn < 10; ++sn) {
        f32x2 p;
        p = __builtin_amdgcn_cvt_pk_f32_fp8(nv0[sn].x, false); s0[0] += p[0]; s0[1] += p[1];
        p = __builtin_amdgcn_cvt_pk_f32_fp8(nv0[sn].x, true);  s0[2] += p[0]; s0[3] += p[1];
        p = __builtin_amdgcn_cvt_pk_f32_fp8(nv0[sn].y, false); s0[4] += p[0]; s0[5] += p[1];
        p = __builtin_amdgcn_cvt_pk_f32_fp8(nv0[sn].y, true);  s0[6] += p[0]; s0[7] += p[1];
    }
    #pragma unroll
    for (int sn = 0; sn < 10; ++sn) {
        f32x2 p;
        p = __builtin_amdgcn_cvt_pk_f32_fp8(nv1[sn].x, false); s1[0] += p[0]; s1[1] += p[1];
        p = __builtin_amdgcn_cvt_pk_f32_fp8(nv1[sn].x, true);  s1[2] += p[0]; s1[3] += p[1];
        p = __builtin_amdgcn_cvt_pk_f32_fp8(nv1[sn].y, false); s1[4] += p[0]; s1[5] += p[1];
        p = __builtin_amdgcn_cvt_pk_f32_fp8(nv1[sn].y, true);  s1[6] += p[0]; s1[7] += p[1];
    }
    bf16x8 o0, o1;
    #pragma unroll
    for (int e = 0; e < 8; ++e) {
        o0[e] = (short)f2bf(s0[e] * 0.1f);
        o1[e] = (short)f2bf(s1[e] * 0.1f);
    }
    *(bf16x8*)&As[r0][128 + c8] = o0;
    *(bf16x8*)&As[r1][128 + c8] = o1;
    __syncthreads();

    // MFMA: wave w -> rows (w&1)*16..+16, cols (w>>1)*64..+64. K=256 via 8 steps.
    const int lane = t & 63;
    const int w = t >> 6;
    const int rows16 = (w & 1) * 16;
    const int cols64 = (w >> 1) * 64;
    const int arow = rows16 + (lane & 15);
    const int ko = (lane >> 4) * 8;
    const int ncol = lane & 15;

    f32x4 acc[4];
    #pragma unroll
    for (int i = 0; i < 4; ++i) acc[i] = (f32x4){0.f, 0.f, 0.f, 0.f};

    #pragma unroll
    for (int kk = 0; kk < 8; ++kk) {
        bf16x8 af = *(const bf16x8*)&As[arow][kk * 32 + ko];
        #pragma unroll
        for (int ct = 0; ct < 4; ++ct) {
            const unsigned short* wp = Wb + (size_t)(cols64 + ct * 16 + ncol) * 256 + kk * 32 + ko;
            bf16x8 bf = *(const bf16x8*)wp;
            acc[ct] = __builtin_amdgcn_mfma_f32_16x16x32_bf16(af, bf, acc[ct], 0, 0, 0);
        }
    }

    // C/D: col = lane&15, row = (lane>>4)*4 + r
    const int mr = rowBase + rows16 + (lane >> 4) * 4;
    #pragma unroll
    for (int ct = 0; ct < 4; ++ct) {
        #pragma unroll
        for (int r = 0; r < 4; ++r) {
            out[(size_t)(mr + r) * 128 + cols64 + ct * 16 + ncol] = f2bf(fmaxf(acc[ct][r], 0.f));
        }
    }
}

// Layer 2 fused, bf16 source (round-3/7 proven config).
template<bool OUT_BF16>
__global__ __launch_bounds__(256, 4)
void sage_layer32(const unsigned short* __restrict__ src,
                  const unsigned short* __restrict__ Wb,
                  const int* __restrict__ self_idx,
                  const int* __restrict__ neigh_idx,
                  void* __restrict__ out_v) {
    __shared__ unsigned short As[32][264];
    __shared__ int sIdx[32];
    __shared__ int nIdx[320];

    const int t = threadIdx.x;
    const int rowBase = blockIdx.x * 32;

    if (t < 32) sIdx[t] = self_idx[rowBase + t];
    for (int i = t; i < 320; i += 256) nIdx[i] = neigh_idx[rowBase * 10 + i];
    __syncthreads();

    const int r0 = t >> 4;
    const int r1 = r0 + 16;
    const int co = (t & 15) * 8;

    bf16x8 sv0 = *(const bf16x8*)(src + (size_t)sIdx[r0] * 128 + co);
    bf16x8 sv1 = *(const bf16x8*)(src + (size_t)sIdx[r1] * 128 + co);
    bf16x8 nv0[10], nv1[10];
    #pragma unroll
    for (int sn = 0; sn < 10; ++sn)
        nv0[sn] = *(const bf16x8*)(src + (size_t)nIdx[r0 * 10 + sn] * 128 + co);
    #pragma unroll
    for (int sn = 0; sn < 10; ++sn)
        nv1[sn] = *(const bf16x8*)(src + (size_t)nIdx[r1 * 10 + sn] * 128 + co);

    *(bf16x8*)&As[r0][co] = sv0;
    *(bf16x8*)&As[r1][co] = sv1;

    float s0[8], s1[8];
    #pragma unroll
    for (int e = 0; e < 8; ++e) { s0[e] = 0.f; s1[e] = 0.f; }
    #pragma unroll
    for (int sn = 0; sn < 10; ++sn) {
        #pragma unroll
        for (int e = 0; e < 8; ++e) s0[e] += bf2f((unsigned short)nv0[sn][e]);
    }
    #pragma unroll
    for (int sn = 0; sn < 10; ++sn) {
        #pragma unroll
        for (int e = 0; e < 8; ++e) s1[e] += bf2f((unsigned short)nv1[sn][e]);
    }
    bf16x8 o0, o1;
    #pragma unroll
    for (int e = 0; e < 8; ++e) {
        o0[e] = (short)f2bf(s0[e] * 0.1f);
        o1[e] = (short)f2bf(s1[e] * 0.1f);
    }
    *(bf16x8*)&As[r0][128 + co] = o0;
    *(bf16x8*)&As[r1][128 + co] = o1;
    __syncthreads();

    const int lane = t & 63;
    const int w = t >> 6;
    const int rows16 = (w & 1) * 16;
    const int cols64 = (w >> 1) * 64;
    const int arow = rows16 + (lane & 15);
    const int ko = (lane >> 4) * 8;
    const int ncol = lane & 15;

    f32x4 acc[4];
    #pragma unroll
    for (int i = 0; i < 4; ++i) acc[i] = (f32x4){0.f, 0.f, 0.f, 0.f};

    #pragma unroll
    for (int kk = 0; kk < 8; ++kk) {
        bf16x8 af = *(const bf16x8*)&As[arow][kk * 32 + ko];
        #pragma unroll
        for (int ct = 0; ct < 4; ++ct) {
            const unsigned short* wp = Wb + (size_t)(cols64 + ct * 16 + ncol) * 256 + kk * 32 + ko;
            bf16x8 bf = *(const bf16x8*)wp;
            acc[ct] = __builtin_amdgcn_mfma_f32_16x16x32_bf16(af, bf, acc[ct], 0, 0, 0);
        }
    }

    const int mr = rowBase + rows16 + (lane >> 4) * 4;
    if (OUT_BF16) {
        unsigned short* out = (unsigned short*)out_v;
        #pragma unroll
        for (int ct = 0; ct < 4; ++ct) {
            #pragma unroll
            for (int r = 0; r < 4; ++r) {
                out[(size_t)(mr + r) * 128 + cols64 + ct * 16 + ncol] = f2bf(fmaxf(acc[ct][r], 0.f));
            }
        }
    } else {
        float* out = (float*)out_v;
        #pragma unroll
        for (int ct = 0; ct < 4; ++ct) {
            #pragma unroll
            for (int r = 0; r < 4; ++r) {
                out[(size_t)(mr + r) * 128 + cols64 + ct * 16 + ncol] = fmaxf(acc[ct][r], 0.f);
            }
        }
    }
}

// ---- Fallback (f32-source) layer kernel, used only if ws is too small ----
template<bool SRC_BF16, bool OUT_BF16>
__global__ __launch_bounds__(256, 2)
void sage_layer(const void* __restrict__ src_v,
                const unsigned short* __restrict__ Wb,
                const int* __restrict__ self_idx,
                const int* __restrict__ neigh_idx,
                void* __restrict__ out_v) {
    __shared__ unsigned short As[64][264];
    __shared__ int sIdx[64];
    __shared__ int nIdx[64][10];

    const int t = threadIdx.x;
    const int rowBase = blockIdx.x * 64;

    if (t < 64) sIdx[t] = self_idx[rowBase + t];
    for (int i = t; i < 640; i += 256) nIdx[i / 10][i % 10] = neigh_idx[rowBase * 10 + i];
    __syncthreads();

    #pragma unroll
    for (int it = 0; it < 16; ++it) {
        int c = it * 256 + t;
        int row = c >> 6;
        int cc = c & 63;
        float4 v;
        if (cc < 32) {
            if constexpr (SRC_BF16) {
                ushort4 u = *(const ushort4*)((const unsigned short*)src_v + (size_t)sIdx[row] * 128 + cc * 4);
                v.x = bf2f(u.x); v.y = bf2f(u.y); v.z = bf2f(u.z); v.w = bf2f(u.w);
            } else {
                v = *(const float4*)((const float*)src_v + (size_t)sIdx[row] * 128 + cc * 4);
            }
        } else {
            int fo = (cc - 32) * 4;
            float sx = 0.f, sy = 0.f, sz = 0.f, sw = 0.f;
            #pragma unroll
            for (int sn = 0; sn < 10; ++sn) {
                float4 x;
                if constexpr (SRC_BF16) {
                    ushort4 u = *(const ushort4*)((const unsigned short*)src_v + (size_t)nIdx[row][sn] * 128 + fo);
                    x.x = bf2f(u.x); x.y = bf2f(u.y); x.z = bf2f(u.z); x.w = bf2f(u.w);
                } else {
                    x = *(const float4*)((const float*)src_v + (size_t)nIdx[row][sn] * 128 + fo);
                }
                sx += x.x; sy += x.y; sz += x.z; sw += x.w;
            }
            v.x = sx * 0.1f; v.y = sy * 0.1f; v.z = sz * 0.1f; v.w = sw * 0.1f;
        }
        ushort4 o;
        o.x = f2bf(v.x); o.y = f2bf(v.y); o.z = f2bf(v.z); o.w = f2bf(v.w);
        *(ushort4*)&As[row][cc * 4] = o;
    }
    __syncthreads();

    const int lane = t & 63;
    const int w = t >> 6;
    const int arow = w * 16 + (lane & 15);
    const int ko = (lane >> 4) * 8;
    const int ncol = lane & 15;

    f32x4 acc[8];
    #pragma unroll
    for (int i = 0; i < 8; ++i) acc[i] = (f32x4){0.f, 0.f, 0.f, 0.f};

    #pragma unroll
    for (int kk = 0; kk < 8; ++kk) {
        bf16x8 af = *(const bf16x8*)&As[arow][kk * 32 + ko];
        #pragma unroll
        for (int ct = 0; ct < 8; ++ct) {
            const unsigned short* wp = Wb + (ct * 16 + ncol) * 256 + kk * 32 + ko;
            bf16x8 bf = *(const bf16x8*)wp;
            acc[ct] = __builtin_amdgcn_mfma_f32_16x16x32_bf16(af, bf, acc[ct], 0, 0, 0);
        }
    }

    const int mr = rowBase + w * 16 + (lane >> 4) * 4;
    if (OUT_BF16) {
        unsigned short* out = (unsigned short*)out_v;
        #pragma unroll
        for (int ct = 0; ct < 8; ++ct) {
            #pragma unroll
            for (int r = 0; r < 4; ++r) {
                out[(size_t)(mr + r) * 128 + ct * 16 + ncol] = f2bf(fmaxf(acc[ct][r], 0.f));
            }
        }
    } else {
        float* out = (float*)out_v;
        #pragma unroll
        for (int ct = 0; ct < 8; ++ct) {
            #pragma unroll
            for (int r = 0; r < 4; ++r) {
                out[(size_t)(mr + r) * 128 + ct * 16 + ncol] = fmaxf(acc[ct][r], 0.f);
            }
        }
    }
}

extern "C" void kernel_launch(void* const* d_in, const int* in_sizes, int n_in,
                              void* d_out, int out_size, void* d_ws, size_t ws_size,
                              hipStream_t stream) {
    const float* raw   = (const float*)d_in[0];   // [200000,128]
    const float* W1    = (const float*)d_in[1];   // [128,256]
    const float* W2    = (const float*)d_in[2];   // [128,256]
    const int* self1   = (const int*)d_in[3];     // [81920]
    const int* neigh1  = (const int*)d_in[4];     // [81920,10]
    const int* self2   = (const int*)d_in[5];     // [8192]
    const int* neigh2  = (const int*)d_in[6];     // [8192,10]
    float* out = (float*)d_out;                   // [8192,128] f32

    char* ws = (char*)d_ws;
    unsigned short* W1b  = (unsigned short*)ws;                        // 32768 elems
    unsigned short* W2b  = W1b + 128 * 256;
    unsigned short* h1   = W2b + 128 * 256;                            // 81920*128 bf16
    unsigned short* rawb = h1 + (size_t)81920 * 128;                   // 200000*128 bf16
    unsigned int*   raw8 = (unsigned int*)(rawb + (size_t)200000 * 128); // 200000*32 u32

    const size_t need = (size_t)(128 * 256 * 2 + 81920 * 128 + (size_t)200000 * 128) * 2
                        + (size_t)200000 * 128;   // + fp8 table

    if (ws_size >= need) {
        cvt_fused<<<12628, 256, 0, stream>>>(raw, W1, W2, rawb, raw8, W1b, W2b);
        sage_layer32_f8<<<81920 / 32, 256, 0, stream>>>(
            rawb, raw8, W1b, self1, neigh1, h1);
        sage_layer32<false><<<8192 / 32, 256, 0, stream>>>(
            h1, W2b, self2, neigh2, (void*)out);
    } else {
        sage_layer<false, true><<<81920 / 64, 256, 0, stream>>>(
            (const void*)raw, W1b, self1, neigh1, (void*)h1);
        sage_layer<true, false><<<8192 / 64, 256, 0, stream>>>(
            (const void*)h1, W2b, self2, neigh2, (void*)out);
    }
}

// Round 10
// 90.627 us; speedup vs baseline: 1.3526x; 1.0247x over previous
//
#include <hip/hip_runtime.h>
#include <hip/hip_bf16.h>

typedef __attribute__((ext_vector_type(4))) float f32x4;
typedef __attribute__((ext_vector_type(2))) float f32x2;
typedef __attribute__((ext_vector_type(8))) short bf16x8;

__device__ __forceinline__ unsigned short f2bf(float f) {
    unsigned int u = __float_as_uint(f);
    u = (u + 0x7FFFu + ((u >> 16) & 1u)) >> 16;
    return (unsigned short)u;
}

__device__ __forceinline__ float bf2f(unsigned short u) {
    return __uint_as_float(((unsigned int)u) << 16);
}

// Conversion: blocks [0,12500) build the fp8 e4m3 neighbor table (200000*128);
// blocks [12500,12628) convert W1|W2 to bf16. No bf16 feature table anymore —
// self rows are read straight from the f32 source in the layer kernel.
__global__ __launch_bounds__(256) void cvt_fused(const float* __restrict__ feat,
                                                 const float* __restrict__ W1,
                                                 const float* __restrict__ W2,
                                                 unsigned int* __restrict__ feat8,
                                                 unsigned short* __restrict__ W1b,
                                                 unsigned short* __restrict__ W2b) {
    if (blockIdx.x < 12500) {
        size_t i = ((size_t)blockIdx.x * 256 + threadIdx.x) * 8;
        f32x4 a = __builtin_nontemporal_load((const f32x4*)(feat + i));
        f32x4 b = __builtin_nontemporal_load((const f32x4*)(feat + i + 4));
        unsigned int p0 = 0, p1 = 0;
        p0 = __builtin_amdgcn_cvt_pk_fp8_f32(a[0], a[1], p0, false);
        p0 = __builtin_amdgcn_cvt_pk_fp8_f32(a[2], a[3], p0, true);
        p1 = __builtin_amdgcn_cvt_pk_fp8_f32(b[0], b[1], p1, false);
        p1 = __builtin_amdgcn_cvt_pk_fp8_f32(b[2], b[3], p1, true);
        uint2 pv; pv.x = p0; pv.y = p1;
        *(uint2*)(feat8 + i / 4) = pv;
    } else {
        int i = (blockIdx.x - 12500) * 256 + threadIdx.x;   // [0, 32768)
        W1b[i] = f2bf(__builtin_nontemporal_load(W1 + i));
        W2b[i] = f2bf(__builtin_nontemporal_load(W2 + i));
    }
}

// Layer 1: out[m] = relu([f32 self | mean_s fp8 neigh] @ W^T), 32 rows/block.
// Neighbor gather re-shaped: 8 lanes/row x 16B (uint4) -> 10 gather
// instructions/thread (was 20), same lines-in-flight. Self rows: f32 direct.
__global__ __launch_bounds__(256, 4)
void sage_layer32_f8(const float* __restrict__ srcf,         // [*,128] f32 (self)
                     const unsigned int* __restrict__ src8,  // [*,32] u32 = 128 fp8
                     const unsigned short* __restrict__ Wb,  // [128][256] bf16
                     const int* __restrict__ self_idx,
                     const int* __restrict__ neigh_idx,
                     unsigned short* __restrict__ out) {     // [M,128] bf16
    __shared__ unsigned short As[32][264];   // [self|agg], +8 pad (row 528B)
    __shared__ int sIdx[32];
    __shared__ int nIdx[320];

    const int t = threadIdx.x;
    const int rowBase = blockIdx.x * 32;

    if (t < 32) sIdx[t] = self_idx[rowBase + t];
    for (int i = t; i < 320; i += 256) nIdx[i] = neigh_idx[rowBase * 10 + i];
    __syncthreads();

    // ---- Self rows (f32 direct): 16 threads/row, 2 rows/thread, 32B each ----
    const int rs0 = t >> 4;          // 0..15
    const int rs1 = rs0 + 16;        // 16..31
    const int co = (t & 15) * 8;     // elem offset (8 f32 = 32B)
    f32x4 sa0 = *(const f32x4*)(srcf + (size_t)sIdx[rs0] * 128 + co);
    f32x4 sb0 = *(const f32x4*)(srcf + (size_t)sIdx[rs0] * 128 + co + 4);
    f32x4 sa1 = *(const f32x4*)(srcf + (size_t)sIdx[rs1] * 128 + co);
    f32x4 sb1 = *(const f32x4*)(srcf + (size_t)sIdx[rs1] * 128 + co + 4);

    // ---- Neighbor gather (fp8): 8 threads/row, 1 row/thread, 16B/load ----
    const int rn = t >> 3;           // 0..31
    const int cu = (t & 7) * 4;      // u32 offset (4 u32 = 16 fp8 elems)
    const int eb = (t & 7) * 16;     // element offset of this thread's 16 elems
    uint4 nv[10];
    #pragma unroll
    for (int sn = 0; sn < 10; ++sn)
        nv[sn] = *(const uint4*)(src8 + (size_t)nIdx[rn * 10 + sn] * 32 + cu);

    // Write self rows (waits only the 4 self loads; neighbors stay in flight).
    {
        bf16x8 o0, o1;
        o0[0] = (short)f2bf(sa0[0]); o0[1] = (short)f2bf(sa0[1]);
        o0[2] = (short)f2bf(sa0[2]); o0[3] = (short)f2bf(sa0[3]);
        o0[4] = (short)f2bf(sb0[0]); o0[5] = (short)f2bf(sb0[1]);
        o0[6] = (short)f2bf(sb0[2]); o0[7] = (short)f2bf(sb0[3]);
        o1[0] = (short)f2bf(sa1[0]); o1[1] = (short)f2bf(sa1[1]);
        o1[2] = (short)f2bf(sa1[2]); o1[3] = (short)f2bf(sa1[3]);
        o1[4] = (short)f2bf(sb1[0]); o1[5] = (short)f2bf(sb1[1]);
        o1[6] = (short)f2bf(sb1[2]); o1[7] = (short)f2bf(sb1[3]);
        *(bf16x8*)&As[rs0][co] = o0;
        *(bf16x8*)&As[rs1][co] = o1;
    }

    // Sum 10 neighbors, 16 elems each.
    float s[16];
    #pragma unroll
    for (int e = 0; e < 16; ++e) s[e] = 0.f;
    #pragma unroll
    for (int sn = 0; sn < 10; ++sn) {
        f32x2 p;
        p = __builtin_amdgcn_cvt_pk_f32_fp8(nv[sn].x, false); s[0]  += p[0]; s[1]  += p[1];
        p = __builtin_amdgcn_cvt_pk_f32_fp8(nv[sn].x, true);  s[2]  += p[0]; s[3]  += p[1];
        p = __builtin_amdgcn_cvt_pk_f32_fp8(nv[sn].y, false); s[4]  += p[0]; s[5]  += p[1];
        p = __builtin_amdgcn_cvt_pk_f32_fp8(nv[sn].y, true);  s[6]  += p[0]; s[7]  += p[1];
        p = __builtin_amdgcn_cvt_pk_f32_fp8(nv[sn].z, false); s[8]  += p[0]; s[9]  += p[1];
        p = __builtin_amdgcn_cvt_pk_f32_fp8(nv[sn].z, true);  s[10] += p[0]; s[11] += p[1];
        p = __builtin_amdgcn_cvt_pk_f32_fp8(nv[sn].w, false); s[12] += p[0]; s[13] += p[1];
        p = __builtin_amdgcn_cvt_pk_f32_fp8(nv[sn].w, true);  s[14] += p[0]; s[15] += p[1];
    }
    {
        bf16x8 oa, ob;
        #pragma unroll
        for (int e = 0; e < 8; ++e) {
            oa[e] = (short)f2bf(s[e] * 0.1f);
            ob[e] = (short)f2bf(s[8 + e] * 0.1f);
        }
        *(bf16x8*)&As[rn][128 + eb] = oa;
        *(bf16x8*)&As[rn][128 + eb + 8] = ob;
    }
    __syncthreads();

    // ---- MFMA: wave w -> rows (w&1)*16..+16, cols (w>>1)*64..+64, K=256 ----
    const int lane = t & 63;
    const int w = t >> 6;
    const int rows16 = (w & 1) * 16;
    const int cols64 = (w >> 1) * 64;
    const int arow = rows16 + (lane & 15);
    const int ko = (lane >> 4) * 8;
    const int ncol = lane & 15;

    f32x4 acc[4];
    #pragma unroll
    for (int i = 0; i < 4; ++i) acc[i] = (f32x4){0.f, 0.f, 0.f, 0.f};

    #pragma unroll
    for (int kk = 0; kk < 8; ++kk) {
        bf16x8 af = *(const bf16x8*)&As[arow][kk * 32 + ko];
        #pragma unroll
        for (int ct = 0; ct < 4; ++ct) {
            const unsigned short* wp = Wb + (size_t)(cols64 + ct * 16 + ncol) * 256 + kk * 32 + ko;
            bf16x8 bf = *(const bf16x8*)wp;
            acc[ct] = __builtin_amdgcn_mfma_f32_16x16x32_bf16(af, bf, acc[ct], 0, 0, 0);
        }
    }

    // C/D: col = lane&15, row = (lane>>4)*4 + r
    const int mr = rowBase + rows16 + (lane >> 4) * 4;
    #pragma unroll
    for (int ct = 0; ct < 4; ++ct) {
        #pragma unroll
        for (int r = 0; r < 4; ++r) {
            out[(size_t)(mr + r) * 128 + cols64 + ct * 16 + ncol] = f2bf(fmaxf(acc[ct][r], 0.f));
        }
    }
}

// Layer 2 fused, bf16 source (round-3/7/9 proven config).
template<bool OUT_BF16>
__global__ __launch_bounds__(256, 4)
void sage_layer32(const unsigned short* __restrict__ src,
                  const unsigned short* __restrict__ Wb,
                  const int* __restrict__ self_idx,
                  const int* __restrict__ neigh_idx,
                  void* __restrict__ out_v) {
    __shared__ unsigned short As[32][264];
    __shared__ int sIdx[32];
    __shared__ int nIdx[320];

    const int t = threadIdx.x;
    const int rowBase = blockIdx.x * 32;

    if (t < 32) sIdx[t] = self_idx[rowBase + t];
    for (int i = t; i < 320; i += 256) nIdx[i] = neigh_idx[rowBase * 10 + i];
    __syncthreads();

    const int r0 = t >> 4;
    const int r1 = r0 + 16;
    const int co = (t & 15) * 8;

    bf16x8 sv0 = *(const bf16x8*)(src + (size_t)sIdx[r0] * 128 + co);
    bf16x8 sv1 = *(const bf16x8*)(src + (size_t)sIdx[r1] * 128 + co);
    bf16x8 nv0[10], nv1[10];
    #pragma unroll
    for (int sn = 0; sn < 10; ++sn)
        nv0[sn] = *(const bf16x8*)(src + (size_t)nIdx[r0 * 10 + sn] * 128 + co);
    #pragma unroll
    for (int sn = 0; sn < 10; ++sn)
        nv1[sn] = *(const bf16x8*)(src + (size_t)nIdx[r1 * 10 + sn] * 128 + co);

    *(bf16x8*)&As[r0][co] = sv0;
    *(bf16x8*)&As[r1][co] = sv1;

    float s0[8], s1[8];
    #pragma unroll
    for (int e = 0; e < 8; ++e) { s0[e] = 0.f; s1[e] = 0.f; }
    #pragma unroll
    for (int sn = 0; sn < 10; ++sn) {
        #pragma unroll
        for (int e = 0; e < 8; ++e) s0[e] += bf2f((unsigned short)nv0[sn][e]);
    }
    #pragma unroll
    for (int sn = 0; sn < 10; ++sn) {
        #pragma unroll
        for (int e = 0; e < 8; ++e) s1[e] += bf2f((unsigned short)nv1[sn][e]);
    }
    bf16x8 o0, o1;
    #pragma unroll
    for (int e = 0; e < 8; ++e) {
        o0[e] = (short)f2bf(s0[e] * 0.1f);
        o1[e] = (short)f2bf(s1[e] * 0.1f);
    }
    *(bf16x8*)&As[r0][128 + co] = o0;
    *(bf16x8*)&As[r1][128 + co] = o1;
    __syncthreads();

    const int lane = t & 63;
    const int w = t >> 6;
    const int rows16 = (w & 1) * 16;
    const int cols64 = (w >> 1) * 64;
    const int arow = rows16 + (lane & 15);
    const int ko = (lane >> 4) * 8;
    const int ncol = lane & 15;

    f32x4 acc[4];
    #pragma unroll
    for (int i = 0; i < 4; ++i) acc[i] = (f32x4){0.f, 0.f, 0.f, 0.f};

    #pragma unroll
    for (int kk = 0; kk < 8; ++kk) {
        bf16x8 af = *(const bf16x8*)&As[arow][kk * 32 + ko];
        #pragma unroll
        for (int ct = 0; ct < 4; ++ct) {
            const unsigned short* wp = Wb + (size_t)(cols64 + ct * 16 + ncol) * 256 + kk * 32 + ko;
            bf16x8 bf = *(const bf16x8*)wp;
            acc[ct] = __builtin_amdgcn_mfma_f32_16x16x32_bf16(af, bf, acc[ct], 0, 0, 0);
        }
    }

    const int mr = rowBase + rows16 + (lane >> 4) * 4;
    if (OUT_BF16) {
        unsigned short* out = (unsigned short*)out_v;
        #pragma unroll
        for (int ct = 0; ct < 4; ++ct) {
            #pragma unroll
            for (int r = 0; r < 4; ++r) {
                out[(size_t)(mr + r) * 128 + cols64 + ct * 16 + ncol] = f2bf(fmaxf(acc[ct][r], 0.f));
            }
        }
    } else {
        float* out = (float*)out_v;
        #pragma unroll
        for (int ct = 0; ct < 4; ++ct) {
            #pragma unroll
            for (int r = 0; r < 4; ++r) {
                out[(size_t)(mr + r) * 128 + cols64 + ct * 16 + ncol] = fmaxf(acc[ct][r], 0.f);
            }
        }
    }
}

// ---- Fallback (f32-source) layer kernel, used only if ws is too small ----
template<bool SRC_BF16, bool OUT_BF16>
__global__ __launch_bounds__(256, 2)
void sage_layer(const void* __restrict__ src_v,
                const unsigned short* __restrict__ Wb,
                const int* __restrict__ self_idx,
                const int* __restrict__ neigh_idx,
                void* __restrict__ out_v) {
    __shared__ unsigned short As[64][264];
    __shared__ int sIdx[64];
    __shared__ int nIdx[64][10];

    const int t = threadIdx.x;
    const int rowBase = blockIdx.x * 64;

    if (t < 64) sIdx[t] = self_idx[rowBase + t];
    for (int i = t; i < 640; i += 256) nIdx[i / 10][i % 10] = neigh_idx[rowBase * 10 + i];
    __syncthreads();

    #pragma unroll
    for (int it = 0; it < 16; ++it) {
        int c = it * 256 + t;
        int row = c >> 6;
        int cc = c & 63;
        float4 v;
        if (cc < 32) {
            if constexpr (SRC_BF16) {
                ushort4 u = *(const ushort4*)((const unsigned short*)src_v + (size_t)sIdx[row] * 128 + cc * 4);
                v.x = bf2f(u.x); v.y = bf2f(u.y); v.z = bf2f(u.z); v.w = bf2f(u.w);
            } else {
                v = *(const float4*)((const float*)src_v + (size_t)sIdx[row] * 128 + cc * 4);
            }
        } else {
            int fo = (cc - 32) * 4;
            float sx = 0.f, sy = 0.f, sz = 0.f, sw = 0.f;
            #pragma unroll
            for (int sn = 0; sn < 10; ++sn) {
                float4 x;
                if constexpr (SRC_BF16) {
                    ushort4 u = *(const ushort4*)((const unsigned short*)src_v + (size_t)nIdx[row][sn] * 128 + fo);
                    x.x = bf2f(u.x); x.y = bf2f(u.y); x.z = bf2f(u.z); x.w = bf2f(u.w);
                } else {
                    x = *(const float4*)((const float*)src_v + (size_t)nIdx[row][sn] * 128 + fo);
                }
                sx += x.x; sy += x.y; sz += x.z; sw += x.w;
            }
            v.x = sx * 0.1f; v.y = sy * 0.1f; v.z = sz * 0.1f; v.w = sw * 0.1f;
        }
        ushort4 o;
        o.x = f2bf(v.x); o.y = f2bf(v.y); o.z = f2bf(v.z); o.w = f2bf(v.w);
        *(ushort4*)&As[row][cc * 4] = o;
    }
    __syncthreads();

    const int lane = t & 63;
    const int w = t >> 6;
    const int arow = w * 16 + (lane & 15);
    const int ko = (lane >> 4) * 8;
    const int ncol = lane & 15;

    f32x4 acc[8];
    #pragma unroll
    for (int i = 0; i < 8; ++i) acc[i] = (f32x4){0.f, 0.f, 0.f, 0.f};

    #pragma unroll
    for (int kk = 0; kk < 8; ++kk) {
        bf16x8 af = *(const bf16x8*)&As[arow][kk * 32 + ko];
        #pragma unroll
        for (int ct = 0; ct < 8; ++ct) {
            const unsigned short* wp = Wb + (ct * 16 + ncol) * 256 + kk * 32 + ko;
            bf16x8 bf = *(const bf16x8*)wp;
            acc[ct] = __builtin_amdgcn_mfma_f32_16x16x32_bf16(af, bf, acc[ct], 0, 0, 0);
        }
    }

    const int mr = rowBase + w * 16 + (lane >> 4) * 4;
    if (OUT_BF16) {
        unsigned short* out = (unsigned short*)out_v;
        #pragma unroll
        for (int ct = 0; ct < 8; ++ct) {
            #pragma unroll
            for (int r = 0; r < 4; ++r) {
                out[(size_t)(mr + r) * 128 + ct * 16 + ncol] = f2bf(fmaxf(acc[ct][r], 0.f));
            }
        }
    } else {
        float* out = (float*)out_v;
        #pragma unroll
        for (int ct = 0; ct < 8; ++ct) {
            #pragma unroll
            for (int r = 0; r < 4; ++r) {
                out[(size_t)(mr + r) * 128 + ct * 16 + ncol] = fmaxf(acc[ct][r], 0.f);
            }
        }
    }
}

extern "C" void kernel_launch(void* const* d_in, const int* in_sizes, int n_in,
                              void* d_out, int out_size, void* d_ws, size_t ws_size,
                              hipStream_t stream) {
    const float* raw   = (const float*)d_in[0];   // [200000,128]
    const float* W1    = (const float*)d_in[1];   // [128,256]
    const float* W2    = (const float*)d_in[2];   // [128,256]
    const int* self1   = (const int*)d_in[3];     // [81920]
    const int* neigh1  = (const int*)d_in[4];     // [81920,10]
    const int* self2   = (const int*)d_in[5];     // [8192]
    const int* neigh2  = (const int*)d_in[6];     // [8192,10]
    float* out = (float*)d_out;                   // [8192,128] f32

    char* ws = (char*)d_ws;
    unsigned short* W1b  = (unsigned short*)ws;                        // 32768 elems
    unsigned short* W2b  = W1b + 128 * 256;
    unsigned short* h1   = W2b + 128 * 256;                            // 81920*128 bf16
    unsigned int*   raw8 = (unsigned int*)(h1 + (size_t)81920 * 128);  // 200000*32 u32

    const size_t need = (size_t)128 * 256 * 2 * 2 + (size_t)81920 * 128 * 2
                        + (size_t)200000 * 128;   // W + h1 + fp8 table ≈ 47MB

    if (ws_size >= need) {
        cvt_fused<<<12628, 256, 0, stream>>>(raw, W1, W2, raw8, W1b, W2b);
        sage_layer32_f8<<<81920 / 32, 256, 0, stream>>>(
            raw, raw8, W1b, self1, neigh1, h1);
        sage_layer32<false><<<8192 / 32, 256, 0, stream>>>(
            h1, W2b, self2, neigh2, (void*)out);
    } else {
        cvt_fused<<<12628, 256, 0, stream>>>(raw, W1, W2, raw8, W1b, W2b);
        sage_layer<false, true><<<81920 / 64, 256, 0, stream>>>(
            (const void*)raw, W1b, self1, neigh1, (void*)h1);
        sage_layer<true, false><<<8192 / 64, 256, 0, stream>>>(
            (const void*)h1, W2b, self2, neigh2, (void*)out);
    }
}

// Round 11
// 90.543 us; speedup vs baseline: 1.3538x; 1.0009x over previous
//
#include <hip/hip_runtime.h>
#include <hip/hip_bf16.h>

typedef __attribute__((ext_vector_type(4))) float f32x4;
typedef __attribute__((ext_vector_type(2))) float f32x2;
typedef __attribute__((ext_vector_type(8))) short bf16x8;

__device__ __forceinline__ unsigned short f2bf(float f) {
    unsigned int u = __float_as_uint(f);
    u = (u + 0x7FFFu + ((u >> 16) & 1u)) >> 16;
    return (unsigned short)u;
}

__device__ __forceinline__ float bf2f(unsigned short u) {
    return __uint_as_float(((unsigned int)u) << 16);
}

// Conversion: blocks [0,12500) build the fp8 e4m3 neighbor table (200000*128);
// blocks [12500,12628) convert W1|W2 to bf16. Self rows are read from f32 source.
// f32 reads nontemporal; fp8 table stores NORMAL (must stay L3-resident for gather).
__global__ __launch_bounds__(256) void cvt_fused(const float* __restrict__ feat,
                                                 const float* __restrict__ W1,
                                                 const float* __restrict__ W2,
                                                 unsigned int* __restrict__ feat8,
                                                 unsigned short* __restrict__ W1b,
                                                 unsigned short* __restrict__ W2b) {
    if (blockIdx.x < 12500) {
        size_t i = ((size_t)blockIdx.x * 256 + threadIdx.x) * 8;
        f32x4 a = __builtin_nontemporal_load((const f32x4*)(feat + i));
        f32x4 b = __builtin_nontemporal_load((const f32x4*)(feat + i + 4));
        unsigned int p0 = 0, p1 = 0;
        p0 = __builtin_amdgcn_cvt_pk_fp8_f32(a[0], a[1], p0, false);
        p0 = __builtin_amdgcn_cvt_pk_fp8_f32(a[2], a[3], p0, true);
        p1 = __builtin_amdgcn_cvt_pk_fp8_f32(b[0], b[1], p1, false);
        p1 = __builtin_amdgcn_cvt_pk_fp8_f32(b[2], b[3], p1, true);
        uint2 pv; pv.x = p0; pv.y = p1;
        *(uint2*)(feat8 + i / 4) = pv;
    } else {
        int i = (blockIdx.x - 12500) * 256 + threadIdx.x;   // [0, 32768)
        W1b[i] = f2bf(__builtin_nontemporal_load(W1 + i));
        W2b[i] = f2bf(__builtin_nontemporal_load(W2 + i));
    }
}

// Layer 1: out[m] = relu([f32 self | mean_s fp8 neigh] @ W^T), 32 rows/block.
// Neighbor gather: r9's proven shape — 16 lanes/row x 8B (uint2), 2 rows/thread.
// Self rows: f32 direct (no bf16 table). launch_bounds(256,4): no spills.
__global__ __launch_bounds__(256, 4)
void sage_layer32_f8(const float* __restrict__ srcf,         // [*,128] f32 (self)
                     const unsigned int* __restrict__ src8,  // [*,32] u32 = 128 fp8
                     const unsigned short* __restrict__ Wb,  // [128][256] bf16
                     const int* __restrict__ self_idx,
                     const int* __restrict__ neigh_idx,
                     unsigned short* __restrict__ out) {     // [M,128] bf16
    __shared__ unsigned short As[32][264];   // [self|agg], +8 pad (row 528B)
    __shared__ int sIdx[32];
    __shared__ int nIdx[320];

    const int t = threadIdx.x;
    const int rowBase = blockIdx.x * 32;

    if (t < 32) sIdx[t] = self_idx[rowBase + t];
    for (int i = t; i < 320; i += 256) nIdx[i] = neigh_idx[rowBase * 10 + i];
    __syncthreads();

    const int r0 = t >> 4;          // rows 0..15
    const int r1 = r0 + 16;         // rows 16..31
    const int co = (t & 15) * 8;    // 8-elem chunk offset within a 128-wide row
    const int cu = (t & 15) * 2;    // u32 offset within a 32-u32 fp8 row

    // Self rows from f32: 2 rows/thread x 8 floats (2x 16B loads each).
    f32x4 sa0 = *(const f32x4*)(srcf + (size_t)sIdx[r0] * 128 + co);
    f32x4 sb0 = *(const f32x4*)(srcf + (size_t)sIdx[r0] * 128 + co + 4);
    f32x4 sa1 = *(const f32x4*)(srcf + (size_t)sIdx[r1] * 128 + co);
    f32x4 sb1 = *(const f32x4*)(srcf + (size_t)sIdx[r1] * 128 + co + 4);

    // Neighbor gather (fp8): 20 x 8B loads (r9 shape).
    uint2 nv0[10], nv1[10];
    #pragma unroll
    for (int sn = 0; sn < 10; ++sn)
        nv0[sn] = *(const uint2*)(src8 + (size_t)nIdx[r0 * 10 + sn] * 32 + cu);
    #pragma unroll
    for (int sn = 0; sn < 10; ++sn)
        nv1[sn] = *(const uint2*)(src8 + (size_t)nIdx[r1 * 10 + sn] * 32 + cu);

    // Write self rows as bf16.
    {
        bf16x8 o0, o1;
        o0[0] = (short)f2bf(sa0[0]); o0[1] = (short)f2bf(sa0[1]);
        o0[2] = (short)f2bf(sa0[2]); o0[3] = (short)f2bf(sa0[3]);
        o0[4] = (short)f2bf(sb0[0]); o0[5] = (short)f2bf(sb0[1]);
        o0[6] = (short)f2bf(sb0[2]); o0[7] = (short)f2bf(sb0[3]);
        o1[0] = (short)f2bf(sa1[0]); o1[1] = (short)f2bf(sa1[1]);
        o1[2] = (short)f2bf(sa1[2]); o1[3] = (short)f2bf(sa1[3]);
        o1[4] = (short)f2bf(sb1[0]); o1[5] = (short)f2bf(sb1[1]);
        o1[6] = (short)f2bf(sb1[2]); o1[7] = (short)f2bf(sb1[3]);
        *(bf16x8*)&As[r0][co] = o0;
        *(bf16x8*)&As[r1][co] = o1;
    }

    // Sum neighbors (hardware fp8->f32 decode, exact).
    float s0[8], s1[8];
    #pragma unroll
    for (int e = 0; e < 8; ++e) { s0[e] = 0.f; s1[e] = 0.f; }
    #pragma unroll
    for (int sn = 0; sn < 10; ++sn) {
        f32x2 p;
        p = __builtin_amdgcn_cvt_pk_f32_fp8(nv0[sn].x, false); s0[0] += p[0]; s0[1] += p[1];
        p = __builtin_amdgcn_cvt_pk_f32_fp8(nv0[sn].x, true);  s0[2] += p[0]; s0[3] += p[1];
        p = __builtin_amdgcn_cvt_pk_f32_fp8(nv0[sn].y, false); s0[4] += p[0]; s0[5] += p[1];
        p = __builtin_amdgcn_cvt_pk_f32_fp8(nv0[sn].y, true);  s0[6] += p[0]; s0[7] += p[1];
    }
    #pragma unroll
    for (int sn = 0; sn < 10; ++sn) {
        f32x2 p;
        p = __builtin_amdgcn_cvt_pk_f32_fp8(nv1[sn].x, false); s1[0] += p[0]; s1[1] += p[1];
        p = __builtin_amdgcn_cvt_pk_f32_fp8(nv1[sn].x, true);  s1[2] += p[0]; s1[3] += p[1];
        p = __builtin_amdgcn_cvt_pk_f32_fp8(nv1[sn].y, false); s1[4] += p[0]; s1[5] += p[1];
        p = __builtin_amdgcn_cvt_pk_f32_fp8(nv1[sn].y, true);  s1[6] += p[0]; s1[7] += p[1];
    }
    {
        bf16x8 o0, o1;
        #pragma unroll
        for (int e = 0; e < 8; ++e) {
            o0[e] = (short)f2bf(s0[e] * 0.1f);
            o1[e] = (short)f2bf(s1[e] * 0.1f);
        }
        *(bf16x8*)&As[r0][128 + co] = o0;
        *(bf16x8*)&As[r1][128 + co] = o1;
    }
    __syncthreads();

    // MFMA: wave w -> rows (w&1)*16..+16, cols (w>>1)*64..+64, K=256 via 8 steps.
    const int lane = t & 63;
    const int w = t >> 6;
    const int rows16 = (w & 1) * 16;
    const int cols64 = (w >> 1) * 64;
    const int arow = rows16 + (lane & 15);
    const int ko = (lane >> 4) * 8;
    const int ncol = lane & 15;

    f32x4 acc[4];
    #pragma unroll
    for (int i = 0; i < 4; ++i) acc[i] = (f32x4){0.f, 0.f, 0.f, 0.f};

    #pragma unroll
    for (int kk = 0; kk < 8; ++kk) {
        bf16x8 af = *(const bf16x8*)&As[arow][kk * 32 + ko];
        #pragma unroll
        for (int ct = 0; ct < 4; ++ct) {
            const unsigned short* wp = Wb + (size_t)(cols64 + ct * 16 + ncol) * 256 + kk * 32 + ko;
            bf16x8 bf = *(const bf16x8*)wp;
            acc[ct] = __builtin_amdgcn_mfma_f32_16x16x32_bf16(af, bf, acc[ct], 0, 0, 0);
        }
    }

    // C/D: col = lane&15, row = (lane>>4)*4 + r
    const int mr = rowBase + rows16 + (lane >> 4) * 4;
    #pragma unroll
    for (int ct = 0; ct < 4; ++ct) {
        #pragma unroll
        for (int r = 0; r < 4; ++r) {
            out[(size_t)(mr + r) * 128 + cols64 + ct * 16 + ncol] = f2bf(fmaxf(acc[ct][r], 0.f));
        }
    }
}

// Layer 2 fused, bf16 source (round-3/7/9 proven config).
template<bool OUT_BF16>
__global__ __launch_bounds__(256, 4)
void sage_layer32(const unsigned short* __restrict__ src,
                  const unsigned short* __restrict__ Wb,
                  const int* __restrict__ self_idx,
                  const int* __restrict__ neigh_idx,
                  void* __restrict__ out_v) {
    __shared__ unsigned short As[32][264];
    __shared__ int sIdx[32];
    __shared__ int nIdx[320];

    const int t = threadIdx.x;
    const int rowBase = blockIdx.x * 32;

    if (t < 32) sIdx[t] = self_idx[rowBase + t];
    for (int i = t; i < 320; i += 256) nIdx[i] = neigh_idx[rowBase * 10 + i];
    __syncthreads();

    const int r0 = t >> 4;
    const int r1 = r0 + 16;
    const int co = (t & 15) * 8;

    bf16x8 sv0 = *(const bf16x8*)(src + (size_t)sIdx[r0] * 128 + co);
    bf16x8 sv1 = *(const bf16x8*)(src + (size_t)sIdx[r1] * 128 + co);
    bf16x8 nv0[10], nv1[10];
    #pragma unroll
    for (int sn = 0; sn < 10; ++sn)
        nv0[sn] = *(const bf16x8*)(src + (size_t)nIdx[r0 * 10 + sn] * 128 + co);
    #pragma unroll
    for (int sn = 0; sn < 10; ++sn)
        nv1[sn] = *(const bf16x8*)(src + (size_t)nIdx[r1 * 10 + sn] * 128 + co);

    *(bf16x8*)&As[r0][co] = sv0;
    *(bf16x8*)&As[r1][co] = sv1;

    float s0[8], s1[8];
    #pragma unroll
    for (int e = 0; e < 8; ++e) { s0[e] = 0.f; s1[e] = 0.f; }
    #pragma unroll
    for (int sn = 0; sn < 10; ++sn) {
        #pragma unroll
        for (int e = 0; e < 8; ++e) s0[e] += bf2f((unsigned short)nv0[sn][e]);
    }
    #pragma unroll
    for (int sn = 0; sn < 10; ++sn) {
        #pragma unroll
        for (int e = 0; e < 8; ++e) s1[e] += bf2f((unsigned short)nv1[sn][e]);
    }
    bf16x8 o0, o1;
    #pragma unroll
    for (int e = 0; e < 8; ++e) {
        o0[e] = (short)f2bf(s0[e] * 0.1f);
        o1[e] = (short)f2bf(s1[e] * 0.1f);
    }
    *(bf16x8*)&As[r0][128 + co] = o0;
    *(bf16x8*)&As[r1][128 + co] = o1;
    __syncthreads();

    const int lane = t & 63;
    const int w = t >> 6;
    const int rows16 = (w & 1) * 16;
    const int cols64 = (w >> 1) * 64;
    const int arow = rows16 + (lane & 15);
    const int ko = (lane >> 4) * 8;
    const int ncol = lane & 15;

    f32x4 acc[4];
    #pragma unroll
    for (int i = 0; i < 4; ++i) acc[i] = (f32x4){0.f, 0.f, 0.f, 0.f};

    #pragma unroll
    for (int kk = 0; kk < 8; ++kk) {
        bf16x8 af = *(const bf16x8*)&As[arow][kk * 32 + ko];
        #pragma unroll
        for (int ct = 0; ct < 4; ++ct) {
            const unsigned short* wp = Wb + (size_t)(cols64 + ct * 16 + ncol) * 256 + kk * 32 + ko;
            bf16x8 bf = *(const bf16x8*)wp;
            acc[ct] = __builtin_amdgcn_mfma_f32_16x16x32_bf16(af, bf, acc[ct], 0, 0, 0);
        }
    }

    const int mr = rowBase + rows16 + (lane >> 4) * 4;
    if (OUT_BF16) {
        unsigned short* out = (unsigned short*)out_v;
        #pragma unroll
        for (int ct = 0; ct < 4; ++ct) {
            #pragma unroll
            for (int r = 0; r < 4; ++r) {
                out[(size_t)(mr + r) * 128 + cols64 + ct * 16 + ncol] = f2bf(fmaxf(acc[ct][r], 0.f));
            }
        }
    } else {
        float* out = (float*)out_v;
        #pragma unroll
        for (int ct = 0; ct < 4; ++ct) {
            #pragma unroll
            for (int r = 0; r < 4; ++r) {
                out[(size_t)(mr + r) * 128 + cols64 + ct * 16 + ncol] = fmaxf(acc[ct][r], 0.f);
            }
        }
    }
}

// ---- Fallback (f32-source) layer kernel, used only if ws is too small ----
template<bool SRC_BF16, bool OUT_BF16>
__global__ __launch_bounds__(256, 2)
void sage_layer(const void* __restrict__ src_v,
                const unsigned short* __restrict__ Wb,
                const int* __restrict__ self_idx,
                const int* __restrict__ neigh_idx,
                void* __restrict__ out_v) {
    __shared__ unsigned short As[64][264];
    __shared__ int sIdx[64];
    __shared__ int nIdx[64][10];

    const int t = threadIdx.x;
    const int rowBase = blockIdx.x * 64;

    if (t < 64) sIdx[t] = self_idx[rowBase + t];
    for (int i = t; i < 640; i += 256) nIdx[i / 10][i % 10] = neigh_idx[rowBase * 10 + i];
    __syncthreads();

    #pragma unroll
    for (int it = 0; it < 16; ++it) {
        int c = it * 256 + t;
        int row = c >> 6;
        int cc = c & 63;
        float4 v;
        if (cc < 32) {
            if constexpr (SRC_BF16) {
                ushort4 u = *(const ushort4*)((const unsigned short*)src_v + (size_t)sIdx[row] * 128 + cc * 4);
                v.x = bf2f(u.x); v.y = bf2f(u.y); v.z = bf2f(u.z); v.w = bf2f(u.w);
            } else {
                v = *(const float4*)((const float*)src_v + (size_t)sIdx[row] * 128 + cc * 4);
            }
        } else {
            int fo = (cc - 32) * 4;
            float sx = 0.f, sy = 0.f, sz = 0.f, sw = 0.f;
            #pragma unroll
            for (int sn = 0; sn < 10; ++sn) {
                float4 x;
                if constexpr (SRC_BF16) {
                    ushort4 u = *(const ushort4*)((const unsigned short*)src_v + (size_t)nIdx[row][sn] * 128 + fo);
                    x.x = bf2f(u.x); x.y = bf2f(u.y); x.z = bf2f(u.z); x.w = bf2f(u.w);
                } else {
                    x = *(const float4*)((const float*)src_v + (size_t)nIdx[row][sn] * 128 + fo);
                }
                sx += x.x; sy += x.y; sz += x.z; sw += x.w;
            }
            v.x = sx * 0.1f; v.y = sy * 0.1f; v.z = sz * 0.1f; v.w = sw * 0.1f;
        }
        ushort4 o;
        o.x = f2bf(v.x); o.y = f2bf(v.y); o.z = f2bf(v.z); o.w = f2bf(v.w);
        *(ushort4*)&As[row][cc * 4] = o;
    }
    __syncthreads();

    const int lane = t & 63;
    const int w = t >> 6;
    const int arow = w * 16 + (lane & 15);
    const int ko = (lane >> 4) * 8;
    const int ncol = lane & 15;

    f32x4 acc[8];
    #pragma unroll
    for (int i = 0; i < 8; ++i) acc[i] = (f32x4){0.f, 0.f, 0.f, 0.f};

    #pragma unroll
    for (int kk = 0; kk < 8; ++kk) {
        bf16x8 af = *(const bf16x8*)&As[arow][kk * 32 + ko];
        #pragma unroll
        for (int ct = 0; ct < 8; ++ct) {
            const unsigned short* wp = Wb + (ct * 16 + ncol) * 256 + kk * 32 + ko;
            bf16x8 bf = *(const bf16x8*)wp;
            acc[ct] = __builtin_amdgcn_mfma_f32_16x16x32_bf16(af, bf, acc[ct], 0, 0, 0);
        }
    }

    const int mr = rowBase + w * 16 + (lane >> 4) * 4;
    if (OUT_BF16) {
        unsigned short* out = (unsigned short*)out_v;
        #pragma unroll
        for (int ct = 0; ct < 8; ++ct) {
            #pragma unroll
            for (int r = 0; r < 4; ++r) {
                out[(size_t)(mr + r) * 128 + ct * 16 + ncol] = f2bf(fmaxf(acc[ct][r], 0.f));
            }
        }
    } else {
        float* out = (float*)out_v;
        #pragma unroll
        for (int ct = 0; ct < 8; ++ct) {
            #pragma unroll
            for (int r = 0; r < 4; ++r) {
                out[(size_t)(mr + r) * 128 + ct * 16 + ncol] = fmaxf(acc[ct][r], 0.f);
            }
        }
    }
}

extern "C" void kernel_launch(void* const* d_in, const int* in_sizes, int n_in,
                              void* d_out, int out_size, void* d_ws, size_t ws_size,
                              hipStream_t stream) {
    const float* raw   = (const float*)d_in[0];   // [200000,128]
    const float* W1    = (const float*)d_in[1];   // [128,256]
    const float* W2    = (const float*)d_in[2];   // [128,256]
    const int* self1   = (const int*)d_in[3];     // [81920]
    const int* neigh1  = (const int*)d_in[4];     // [81920,10]
    const int* self2   = (const int*)d_in[5];     // [8192]
    const int* neigh2  = (const int*)d_in[6];     // [8192,10]
    float* out = (float*)d_out;                   // [8192,128] f32

    char* ws = (char*)d_ws;
    unsigned short* W1b  = (unsigned short*)ws;                        // 32768 elems
    unsigned short* W2b  = W1b + 128 * 256;
    unsigned short* h1   = W2b + 128 * 256;                            // 81920*128 bf16
    unsigned int*   raw8 = (unsigned int*)(h1 + (size_t)81920 * 128);  // 200000*32 u32

    const size_t need = (size_t)128 * 256 * 2 * 2 + (size_t)81920 * 128 * 2
                        + (size_t)200000 * 128;   // W + h1 + fp8 table ≈ 47MB

    if (ws_size >= need) {
        cvt_fused<<<12628, 256, 0, stream>>>(raw, W1, W2, raw8, W1b, W2b);
        sage_layer32_f8<<<81920 / 32, 256, 0, stream>>>(
            raw, raw8, W1b, self1, neigh1, h1);
        sage_layer32<false><<<8192 / 32, 256, 0, stream>>>(
            h1, W2b, self2, neigh2, (void*)out);
    } else {
        cvt_fused<<<12628, 256, 0, stream>>>(raw, W1, W2, raw8, W1b, W2b);
        sage_layer<false, true><<<81920 / 64, 256, 0, stream>>>(
            (const void*)raw, W1b, self1, neigh1, (void*)h1);
        sage_layer<true, false><<<8192 / 64, 256, 0, stream>>>(
            (const void*)h1, W2b, self2, neigh2, (void*)out);
    }
}